// Round 5
// baseline (327.575 us; speedup 1.0000x reference)
//
#include <hip/hip_runtime.h>

#define N_NODES 100000
#define N_EDGES 800000
#define FDIM 64
#define NSLICE 8            // feature slices: 64/8 = 8 features per slice
#define SLICE_F 8           // floats per node per slice (32 B)
#define SCAN_BLOCK 1024
#define N_SCAN_BLOCKS ((N_NODES + SCAN_BLOCK - 1) / SCAN_BLOCK)   // 98

// ---------------------------------------------------------------------------
// Kernel 1: xw = x @ w, written SLICE-MAJOR: xws[s][node][8], s = f>>3.
// R4 fix: W column in REGISTERS (64 VGPRs/lane), zero ds_read in the loop.
// R3's version issued 64 ds_read_b32/row = 6.4M total ~= 60us of LDS pipe
// (5.8 cyc each, m134) — that WAS the measured 64us floor. W is 16KB ->
// L1-resident global loads, once per wave.
// Fused: zero the degree counts (saves a kernel).
// ---------------------------------------------------------------------------
__global__ __launch_bounds__(256) void gemm_slice_kernel(
    const float* __restrict__ x, const float* __restrict__ w,
    float* __restrict__ xws, int* __restrict__ count) {
    const int gtid = blockIdx.x * 256 + threadIdx.x;
    if (gtid < N_NODES) count[gtid] = 0;    // grid 2048*256 >= N_NODES

    const int lane = threadIdx.x & 63;
    // W column `lane` -> registers. Coalesced across lanes; L1 after wave 0.
    float wr[FDIM];
    #pragma unroll
    for (int k = 0; k < FDIM; ++k) wr[k] = w[k * FDIM + lane];

    const int gwave = blockIdx.x * 4 + (threadIdx.x >> 6);
    const int nwaves = gridDim.x * 4;
    // this lane's output slot: slice (lane>>3), feature-in-slice (lane&7)
    float* const sb = xws + (size_t)(lane >> 3) * N_NODES * SLICE_F + (lane & 7);

    for (int row = gwave; row < N_NODES; row += nwaves) {
        const float4* xr = reinterpret_cast<const float4*>(x + (size_t)row * FDIM);
        float a0 = 0.f, a1 = 0.f, a2 = 0.f, a3 = 0.f;
        #pragma unroll
        for (int k0 = 0; k0 < FDIM / 4; ++k0) {   // FULL unroll: wr[] stays in regs
            float4 xv = xr[k0];                   // wave-uniform address
            a0 += xv.x * wr[4 * k0 + 0];
            a1 += xv.y * wr[4 * k0 + 1];
            a2 += xv.z * wr[4 * k0 + 2];
            a3 += xv.w * wr[4 * k0 + 3];
        }
        sb[(size_t)row * SLICE_F] = (a0 + a1) + (a2 + a3);
    }
}

// ---------------------------------------------------------------------------
// Kernel 2: degree histogram — 4 edges/thread, 4 atomics in flight.
// ---------------------------------------------------------------------------
__global__ __launch_bounds__(256) void hist_kernel(
    const int* __restrict__ erow, int* __restrict__ count) {
    const int base = (blockIdx.x * 256 + threadIdx.x) * 4;
    if (base + 3 < N_EDGES) {
        int4 r = *reinterpret_cast<const int4*>(erow + base);
        atomicAdd(&count[r.x], 1);
        atomicAdd(&count[r.y], 1);
        atomicAdd(&count[r.z], 1);
        atomicAdd(&count[r.w], 1);
    } else {
        for (int e = base; e < N_EDGES; ++e) atomicAdd(&count[erow[e]], 1);
    }
}

// ---------------------------------------------------------------------------
// Kernel 3: per-1024-block scan -> block-local exclusive starts + block sums
// ---------------------------------------------------------------------------
__global__ __launch_bounds__(SCAN_BLOCK) void scan_block_kernel(
    const int* __restrict__ count, int* __restrict__ starts,
    int* __restrict__ blockSums) {
    __shared__ int tmp[SCAN_BLOCK];
    const int tid = threadIdx.x;
    const int i = blockIdx.x * SCAN_BLOCK + tid;
    const int v = (i < N_NODES) ? count[i] : 0;
    tmp[tid] = v;
    __syncthreads();
    for (int off = 1; off < SCAN_BLOCK; off <<= 1) {
        int t = (tid >= off) ? tmp[tid - off] : 0;
        __syncthreads();
        tmp[tid] += t;
        __syncthreads();
    }
    if (i < N_NODES) starts[i] = tmp[tid] - v;
    if (tid == SCAN_BLOCK - 1) blockSums[blockIdx.x] = tmp[tid];
}

// ---------------------------------------------------------------------------
// Kernel 4: every block redundantly scans the 98 block sums in LDS, adds
// offset, writes final starts + cursor + CSR sentinel.
// ---------------------------------------------------------------------------
__global__ __launch_bounds__(256) void scanadd_kernel(
    int* __restrict__ starts, const int* __restrict__ blockSums,
    int* __restrict__ cursor) {
    __shared__ int ssum[128];
    const int tid = threadIdx.x;
    if (tid < 128) ssum[tid] = (tid < N_SCAN_BLOCKS) ? blockSums[tid] : 0;
    __syncthreads();
    for (int off = 1; off < 128; off <<= 1) {
        int t = (tid < 128 && tid >= off) ? ssum[tid - off] : 0;
        __syncthreads();
        if (tid < 128) ssum[tid] += t;   // inclusive
        __syncthreads();
    }
    const int i = blockIdx.x * 256 + tid;
    if (i < N_NODES) {
        const int j = i >> 10;
        const int add = (j == 0) ? 0 : ssum[j - 1];
        const int s = starts[i] + add;
        starts[i] = s;
        cursor[i] = s;
    } else if (i == N_NODES) {
        starts[N_NODES] = N_EDGES;
    }
}

// ---------------------------------------------------------------------------
// Kernel 5: bucket fill -> packed (col, weight_bits) 8B records.
// ---------------------------------------------------------------------------
__global__ __launch_bounds__(256) void fill_kernel(
    const int* __restrict__ erow, const int* __restrict__ ecol,
    const float* __restrict__ ew, int* __restrict__ cursor,
    uint2* __restrict__ recs) {
    const int base = (blockIdx.x * 256 + threadIdx.x) * 4;
    if (base + 3 < N_EDGES) {
        int4 r = *reinterpret_cast<const int4*>(erow + base);
        int4 c = *reinterpret_cast<const int4*>(ecol + base);
        float4 wt = *reinterpret_cast<const float4*>(ew + base);
        int p0 = atomicAdd(&cursor[r.x], 1);
        int p1 = atomicAdd(&cursor[r.y], 1);
        int p2 = atomicAdd(&cursor[r.z], 1);
        int p3 = atomicAdd(&cursor[r.w], 1);
        recs[p0] = make_uint2((unsigned)c.x, __float_as_uint(wt.x));
        recs[p1] = make_uint2((unsigned)c.y, __float_as_uint(wt.y));
        recs[p2] = make_uint2((unsigned)c.z, __float_as_uint(wt.z));
        recs[p3] = make_uint2((unsigned)c.w, __float_as_uint(wt.w));
    } else {
        for (int e = base; e < N_EDGES; ++e) {
            int p = atomicAdd(&cursor[erow[e]], 1);
            recs[p] = make_uint2((unsigned)ecol[e], __float_as_uint(ew[e]));
        }
    }
}

// ---------------------------------------------------------------------------
// Kernel 6: sliced aggregate. Block bid&7 = slice s works ONLY on the 3.2 MB
// slice xws[s] -> L2-resident on its XCD (blocks round-robin XCDs by bid%8).
// 8 lanes per row (one feature each), 8 rows per wave. Gathers become L2
// hits instead of 165 MB of L3 traffic. recs re-streamed 8x (cheap, 51 MB).
// ---------------------------------------------------------------------------
__global__ __launch_bounds__(256) void aggregate_slice_kernel(
    const float* __restrict__ xws, const uint2* __restrict__ recs,
    const int* __restrict__ starts, const float* __restrict__ b,
    float* __restrict__ out) {
    const int s = blockIdx.x & 7;                 // slice = XCD (heuristic)
    const int lane = threadIdx.x & 63;
    const int g = lane >> 3;                      // row slot (8 per wave)
    const int fp = lane & 7;                      // feature within slice
    const int wslice = (int)((blockIdx.x >> 3) * (blockDim.x >> 6) + (threadIdx.x >> 6));
    const int nwslice = (int)((gridDim.x >> 3) * (blockDim.x >> 6));   // 1024

    const float* const sb = xws + (size_t)s * N_NODES * SLICE_F + fp;
    const float bias = b[s * SLICE_F + fp];

    for (int r0 = wslice * 8; r0 < N_NODES; r0 += nwslice * 8) {
        const int r = r0 + g;
        if (r < N_NODES) {
            const int st = starts[r];
            const int cnt = starts[r + 1] - st;
            float acc = bias, acc2 = 0.f;
            int k = 0;
            for (; k + 2 <= cnt; k += 2) {
                uint2 e0 = recs[st + k];          // 8-lane broadcast
                uint2 e1 = recs[st + k + 1];
                float v0 = sb[(size_t)e0.x * SLICE_F];   // L2-resident gather
                float v1 = sb[(size_t)e1.x * SLICE_F];
                acc  += v0 * __uint_as_float(e0.y);
                acc2 += v1 * __uint_as_float(e1.y);
            }
            if (k < cnt) {
                uint2 e0 = recs[st + k];
                acc += sb[(size_t)e0.x * SLICE_F] * __uint_as_float(e0.y);
            }
            out[(size_t)r * FDIM + s * SLICE_F + fp] = acc + acc2;
        }
    }
}

// --------------------------- atomic fallback -------------------------------
// (never taken in practice — ws_size proved sufficient in R4 — kept for safety)
__global__ __launch_bounds__(256) void gemm_rm_kernel(
    const float* __restrict__ x, const float* __restrict__ w,
    float* __restrict__ xw) {
    const int lane = threadIdx.x & 63;
    float wr[FDIM];
    #pragma unroll
    for (int k = 0; k < FDIM; ++k) wr[k] = w[k * FDIM + lane];
    const int gwave = blockIdx.x * 4 + (threadIdx.x >> 6);
    const int nwaves = gridDim.x * 4;
    for (int row = gwave; row < N_NODES; row += nwaves) {
        const float4* xr = reinterpret_cast<const float4*>(x + (size_t)row * FDIM);
        float a0 = 0.f, a1 = 0.f, a2 = 0.f, a3 = 0.f;
        #pragma unroll
        for (int k0 = 0; k0 < FDIM / 4; ++k0) {
            float4 xv = xr[k0];
            a0 += xv.x * wr[4 * k0 + 0];
            a1 += xv.y * wr[4 * k0 + 1];
            a2 += xv.z * wr[4 * k0 + 2];
            a3 += xv.w * wr[4 * k0 + 3];
        }
        xw[(size_t)row * FDIM + lane] = (a0 + a1) + (a2 + a3);
    }
}

__global__ __launch_bounds__(256) void init_out_kernel(
    float* __restrict__ out, const float* __restrict__ b) {
    const float4* b4 = reinterpret_cast<const float4*>(b);
    float4* out4 = reinterpret_cast<float4*>(out);
    const size_t total = (size_t)N_NODES * FDIM / 4;
    size_t i = (size_t)blockIdx.x * blockDim.x + threadIdx.x;
    const size_t stride = (size_t)gridDim.x * blockDim.x;
    for (; i < total; i += stride) out4[i] = b4[i & 15];
}

__global__ __launch_bounds__(256) void scatter_kernel(
    const float* __restrict__ xw, const float* __restrict__ ew,
    const int* __restrict__ erow, const int* __restrict__ ecol,
    float* __restrict__ out) {
    const int lane = threadIdx.x & 63;
    const int g = lane >> 4;
    const int s = lane & 15;
    const int wave = (int)((blockIdx.x * blockDim.x + threadIdx.x) >> 6);
    const int nwaves = (int)((gridDim.x * (size_t)blockDim.x) >> 6);
    for (int e0 = wave * 4; e0 < N_EDGES; e0 += nwaves * 4) {
        const int e = e0 + g;
        if (e < N_EDGES) {
            const int c = ecol[e];
            const int r = erow[e];
            const float wgt = ew[e];
            const float4 v =
                reinterpret_cast<const float4*>(xw + (size_t)c * FDIM)[s];
            float* dst = out + (size_t)r * FDIM + 4 * s;
            atomicAdd(dst + 0, v.x * wgt);
            atomicAdd(dst + 1, v.y * wgt);
            atomicAdd(dst + 2, v.z * wgt);
            atomicAdd(dst + 3, v.w * wgt);
        }
    }
}

extern "C" void kernel_launch(void* const* d_in, const int* in_sizes, int n_in,
                              void* d_out, int out_size, void* d_ws, size_t ws_size,
                              hipStream_t stream) {
    const float* x  = (const float*)d_in[0];
    const float* w  = (const float*)d_in[1];
    const float* b  = (const float*)d_in[2];
    const float* ew = (const float*)d_in[3];
    const int* erow = (const int*)d_in[4];
    const int* ecol = (const int*)d_in[5];
    float* out = (float*)d_out;

    char* ws = (char*)d_ws;
    const size_t XW_BYTES   = (size_t)N_NODES * FDIM * 4;      // 25.6 MB
    const size_t REC_BYTES  = (size_t)N_EDGES * 8;             // 6.4 MB
    const size_t CNT_BYTES  = (size_t)N_NODES * 4;             // 0.4 MB
    const size_t ST_BYTES   = ((size_t)(N_NODES + 1) * 4 + 15) & ~(size_t)15;
    const size_t SUMS_BYTES = 512;
    const size_t NEED = XW_BYTES + REC_BYTES + CNT_BYTES + ST_BYTES +
                        CNT_BYTES + SUMS_BYTES;                // ~33.6 MB

    float* xws = (float*)ws;   // slice-major [8][N_NODES][8]

    if (ws_size >= NEED) {
        uint2* recs    = (uint2*)(ws + XW_BYTES);
        int* count     = (int*)(ws + XW_BYTES + REC_BYTES);
        int* starts    = (int*)(ws + XW_BYTES + REC_BYTES + CNT_BYTES);
        int* cursor    = (int*)(ws + XW_BYTES + REC_BYTES + CNT_BYTES + ST_BYTES);
        int* blockSums = (int*)(ws + XW_BYTES + REC_BYTES + CNT_BYTES + ST_BYTES + CNT_BYTES);

        const int gE4 = (N_EDGES / 4 + 255) / 256;   // 782
        const int gN  = (N_NODES + 255) / 256 + 1;   // 392 (covers sentinel)

        gemm_slice_kernel<<<2048, 256, 0, stream>>>(x, w, xws, count);
        hist_kernel<<<gE4, 256, 0, stream>>>(erow, count);
        scan_block_kernel<<<N_SCAN_BLOCKS, SCAN_BLOCK, 0, stream>>>(count, starts, blockSums);
        scanadd_kernel<<<gN, 256, 0, stream>>>(starts, blockSums, cursor);
        fill_kernel<<<gE4, 256, 0, stream>>>(erow, ecol, ew, cursor, recs);
        aggregate_slice_kernel<<<2048, 256, 0, stream>>>(xws, recs, starts, b, out);
    } else {
        gemm_rm_kernel<<<2048, 256, 0, stream>>>(x, w, (float*)ws);
        init_out_kernel<<<2048, 256, 0, stream>>>(out, b);
        scatter_kernel<<<2048, 256, 0, stream>>>((float*)ws, ew, erow, ecol, out);
    }
}

// Round 8
// 263.653 us; speedup vs baseline: 1.2424x; 1.2424x over previous
//
#include <hip/hip_runtime.h>

#define N_NODES 100000
#define N_EDGES 800000
#define FDIM 64
#define SCAN_BLOCK 1024
#define N_SCAN_BLOCKS ((N_NODES + SCAN_BLOCK - 1) / SCAN_BLOCK)   // 98

// ---------------------------------------------------------------------------
// Kernel 1: xw = x @ w (row-major out). R5 post-mortem: W-in-regs killed
// occupancy (VGPR 116 -> 20% occ -> latency-bound, 103us). R4's W-in-LDS ran
// 60% occ but was LDS-pipe-bound (64 ds_read_b32/row = 60us). Fix BOTH:
//   - W in LDS, quad-transposed: wq[k0][f][j] = w[4k0+j][f], so ONE
//     ds_read_b128 per k0 gives the 4 W values -> 16 b128 per 8 rows
//     = 2 ds_read/row (32x fewer LDS ops than R4).
//   - 8 rows per wave: W-read cost amortized; 8 independent FMA chains.
// Per-CU floor: LDS ~4us, VALU ~8us, HBM 51.2MB ~8us.
// N_NODES % 8 == 0, so no tail handling inside the 8-row group.
// ---------------------------------------------------------------------------
__global__ __launch_bounds__(256) void gemm8_kernel(
    const float* __restrict__ x, const float* __restrict__ w,
    float* __restrict__ xw, int* __restrict__ count) {
    const int tid = threadIdx.x;
    const int gtid = blockIdx.x * 256 + tid;
    if (gtid < N_NODES) count[gtid] = 0;   // fused zero (grid covers N_NODES)

    // wq layout: [k0=0..15][f=0..63][j=0..3] floats
    __shared__ float wq[16 * 64 * 4];
    // stage + quad-transpose: thread reads w[k][f0..f0+3] (float4), writes
    // 4 scalars wq[(k>>2)*256 + (f0+i)*4 + (k&3)]. 4096 floats, 4 iters.
    {
        const float4* w4 = reinterpret_cast<const float4*>(w);
        #pragma unroll
        for (int i = 0; i < 4; ++i) {
            const int idx = i * 256 + tid;       // idx = k*16 + f0/4
            const int k = idx >> 4;
            const int f0 = (idx & 15) * 4;
            float4 v = w4[idx];
            const int base = (k >> 2) * 256 + (k & 3);
            wq[base + (f0 + 0) * 4] = v.x;
            wq[base + (f0 + 1) * 4] = v.y;
            wq[base + (f0 + 2) * 4] = v.z;
            wq[base + (f0 + 3) * 4] = v.w;
        }
    }
    __syncthreads();

    const int lane = tid & 63;
    const int gwave = blockIdx.x * 4 + (tid >> 6);
    const int nwaves = gridDim.x * 4;
    const float4* wqv = reinterpret_cast<const float4*>(wq);

    for (int r0 = gwave * 8; r0 < N_NODES; r0 += nwaves * 8) {
        const float4* xr = reinterpret_cast<const float4*>(x + (size_t)r0 * FDIM);
        float acc[8] = {0.f, 0.f, 0.f, 0.f, 0.f, 0.f, 0.f, 0.f};
        #pragma unroll 2
        for (int k0 = 0; k0 < 16; ++k0) {
            // one b128: the 4 W values for (k=4k0..4k0+3, feature=lane)
            float4 wv = wqv[k0 * 64 + lane];
            #pragma unroll
            for (int rr = 0; rr < 8; ++rr) {
                float4 xv = xr[rr * 16 + k0];   // wave-uniform, imm offset
                acc[rr] += xv.x * wv.x + xv.y * wv.y + xv.z * wv.z + xv.w * wv.w;
            }
        }
        #pragma unroll
        for (int rr = 0; rr < 8; ++rr)
            xw[(size_t)(r0 + rr) * FDIM + lane] = acc[rr];   // 256B coalesced
    }
}

// ---------------------------------------------------------------------------
// Kernel 2: degree histogram — 4 edges/thread, 4 atomics in flight.
// ---------------------------------------------------------------------------
__global__ __launch_bounds__(256) void hist_kernel(
    const int* __restrict__ erow, int* __restrict__ count) {
    const int base = (blockIdx.x * 256 + threadIdx.x) * 4;
    if (base + 3 < N_EDGES) {
        int4 r = *reinterpret_cast<const int4*>(erow + base);
        atomicAdd(&count[r.x], 1);
        atomicAdd(&count[r.y], 1);
        atomicAdd(&count[r.z], 1);
        atomicAdd(&count[r.w], 1);
    } else {
        for (int e = base; e < N_EDGES; ++e) atomicAdd(&count[erow[e]], 1);
    }
}

// ---------------------------------------------------------------------------
// Kernel 3: per-1024-block scan -> block-local exclusive starts + block sums
// ---------------------------------------------------------------------------
__global__ __launch_bounds__(SCAN_BLOCK) void scan_block_kernel(
    const int* __restrict__ count, int* __restrict__ starts,
    int* __restrict__ blockSums) {
    __shared__ int tmp[SCAN_BLOCK];
    const int tid = threadIdx.x;
    const int i = blockIdx.x * SCAN_BLOCK + tid;
    const int v = (i < N_NODES) ? count[i] : 0;
    tmp[tid] = v;
    __syncthreads();
    for (int off = 1; off < SCAN_BLOCK; off <<= 1) {
        int t = (tid >= off) ? tmp[tid - off] : 0;
        __syncthreads();
        tmp[tid] += t;
        __syncthreads();
    }
    if (i < N_NODES) starts[i] = tmp[tid] - v;
    if (tid == SCAN_BLOCK - 1) blockSums[blockIdx.x] = tmp[tid];
}

// ---------------------------------------------------------------------------
// Kernel 4: redundant block-sum scan in LDS + offset add + sentinel.
// ---------------------------------------------------------------------------
__global__ __launch_bounds__(256) void scanadd_kernel(
    int* __restrict__ starts, const int* __restrict__ blockSums,
    int* __restrict__ cursor) {
    __shared__ int ssum[128];
    const int tid = threadIdx.x;
    if (tid < 128) ssum[tid] = (tid < N_SCAN_BLOCKS) ? blockSums[tid] : 0;
    __syncthreads();
    for (int off = 1; off < 128; off <<= 1) {
        int t = (tid < 128 && tid >= off) ? ssum[tid - off] : 0;
        __syncthreads();
        if (tid < 128) ssum[tid] += t;   // inclusive
        __syncthreads();
    }
    const int i = blockIdx.x * 256 + tid;
    if (i < N_NODES) {
        const int j = i >> 10;
        const int add = (j == 0) ? 0 : ssum[j - 1];
        const int s = starts[i] + add;
        starts[i] = s;
        cursor[i] = s;
    } else if (i == N_NODES) {
        starts[N_NODES] = N_EDGES;
    }
}

// ---------------------------------------------------------------------------
// Kernel 5: bucket fill -> packed (col, weight_bits) 8B records.
// ---------------------------------------------------------------------------
__global__ __launch_bounds__(256) void fill_kernel(
    const int* __restrict__ erow, const int* __restrict__ ecol,
    const float* __restrict__ ew, int* __restrict__ cursor,
    uint2* __restrict__ recs) {
    const int base = (blockIdx.x * 256 + threadIdx.x) * 4;
    if (base + 3 < N_EDGES) {
        int4 r = *reinterpret_cast<const int4*>(erow + base);
        int4 c = *reinterpret_cast<const int4*>(ecol + base);
        float4 wt = *reinterpret_cast<const float4*>(ew + base);
        int p0 = atomicAdd(&cursor[r.x], 1);
        int p1 = atomicAdd(&cursor[r.y], 1);
        int p2 = atomicAdd(&cursor[r.z], 1);
        int p3 = atomicAdd(&cursor[r.w], 1);
        recs[p0] = make_uint2((unsigned)c.x, __float_as_uint(wt.x));
        recs[p1] = make_uint2((unsigned)c.y, __float_as_uint(wt.y));
        recs[p2] = make_uint2((unsigned)c.z, __float_as_uint(wt.z));
        recs[p3] = make_uint2((unsigned)c.w, __float_as_uint(wt.w));
    } else {
        for (int e = base; e < N_EDGES; ++e) {
            int p = atomicAdd(&cursor[erow[e]], 1);
            recs[p] = make_uint2((unsigned)ecol[e], __float_as_uint(ew[e]));
        }
    }
}

// ---------------------------------------------------------------------------
// Kernel 6: aggregate — R4 flat structure (slicing regressed ~28us in R5:
// the recs stream thrashed the 4MiB L2 the slice was meant to live in).
// 16 lanes/row, float4/lane, CSR, x4 unroll for gather MLP.
// recs loaded NON-TEMPORAL (stream-once) so they don't evict xw from L2.
// ---------------------------------------------------------------------------
__global__ __launch_bounds__(256) void aggregate_kernel(
    const float* __restrict__ xw, const uint2* __restrict__ recs,
    const int* __restrict__ starts, const float* __restrict__ b,
    float* __restrict__ out) {
    const int lane = threadIdx.x & 63;
    const int g = lane >> 4;        // row slot within wave
    const int s = lane & 15;        // feature quad
    const int wave = (int)((blockIdx.x * blockDim.x + threadIdx.x) >> 6);
    const int nwaves = (int)((gridDim.x * (size_t)blockDim.x) >> 6);
    const float4 bias = reinterpret_cast<const float4*>(b)[s];
    const float4* xw4 = reinterpret_cast<const float4*>(xw);
    const unsigned long long* recs8 =
        reinterpret_cast<const unsigned long long*>(recs);

    for (int r0 = wave * 4; r0 < N_NODES; r0 += nwaves * 4) {
        const int r = r0 + g;
        if (r < N_NODES) {
            const int st = starts[r];
            const int cnt = starts[r + 1] - st;
            float4 acc = bias;
            int k = 0;
            for (; k + 4 <= cnt; k += 4) {
                unsigned long long p0 = __builtin_nontemporal_load(recs8 + st + k + 0);
                unsigned long long p1 = __builtin_nontemporal_load(recs8 + st + k + 1);
                unsigned long long p2 = __builtin_nontemporal_load(recs8 + st + k + 2);
                unsigned long long p3 = __builtin_nontemporal_load(recs8 + st + k + 3);
                float4 v0 = xw4[(size_t)(unsigned)p0 * 16 + s];
                float4 v1 = xw4[(size_t)(unsigned)p1 * 16 + s];
                float4 v2 = xw4[(size_t)(unsigned)p2 * 16 + s];
                float4 v3 = xw4[(size_t)(unsigned)p3 * 16 + s];
                const float w0 = __uint_as_float((unsigned)(p0 >> 32));
                const float w1 = __uint_as_float((unsigned)(p1 >> 32));
                const float w2 = __uint_as_float((unsigned)(p2 >> 32));
                const float w3 = __uint_as_float((unsigned)(p3 >> 32));
                acc.x += v0.x * w0 + v1.x * w1 + v2.x * w2 + v3.x * w3;
                acc.y += v0.y * w0 + v1.y * w1 + v2.y * w2 + v3.y * w3;
                acc.z += v0.z * w0 + v1.z * w1 + v2.z * w2 + v3.z * w3;
                acc.w += v0.w * w0 + v1.w * w1 + v2.w * w2 + v3.w * w3;
            }
            for (; k < cnt; ++k) {
                unsigned long long p0 = __builtin_nontemporal_load(recs8 + st + k);
                float4 v0 = xw4[(size_t)(unsigned)p0 * 16 + s];
                const float w0 = __uint_as_float((unsigned)(p0 >> 32));
                acc.x += v0.x * w0; acc.y += v0.y * w0;
                acc.z += v0.z * w0; acc.w += v0.w * w0;
            }
            reinterpret_cast<float4*>(out + (size_t)r * FDIM)[s] = acc;
        }
    }
}

// --------------------------- atomic fallback -------------------------------
__global__ __launch_bounds__(256) void gemm_rm_kernel(
    const float* __restrict__ x, const float* __restrict__ w,
    float* __restrict__ xw) {
    const int lane = threadIdx.x & 63;
    float wr[FDIM];
    #pragma unroll
    for (int k = 0; k < FDIM; ++k) wr[k] = w[k * FDIM + lane];
    const int gwave = blockIdx.x * 4 + (threadIdx.x >> 6);
    const int nwaves = gridDim.x * 4;
    for (int row = gwave; row < N_NODES; row += nwaves) {
        const float4* xr = reinterpret_cast<const float4*>(x + (size_t)row * FDIM);
        float a0 = 0.f, a1 = 0.f, a2 = 0.f, a3 = 0.f;
        #pragma unroll
        for (int k0 = 0; k0 < FDIM / 4; ++k0) {
            float4 xv = xr[k0];
            a0 += xv.x * wr[4 * k0 + 0];
            a1 += xv.y * wr[4 * k0 + 1];
            a2 += xv.z * wr[4 * k0 + 2];
            a3 += xv.w * wr[4 * k0 + 3];
        }
        xw[(size_t)row * FDIM + lane] = (a0 + a1) + (a2 + a3);
    }
}

__global__ __launch_bounds__(256) void init_out_kernel(
    float* __restrict__ out, const float* __restrict__ b) {
    const float4* b4 = reinterpret_cast<const float4*>(b);
    float4* out4 = reinterpret_cast<float4*>(out);
    const size_t total = (size_t)N_NODES * FDIM / 4;
    size_t i = (size_t)blockIdx.x * blockDim.x + threadIdx.x;
    const size_t stride = (size_t)gridDim.x * blockDim.x;
    for (; i < total; i += stride) out4[i] = b4[i & 15];
}

__global__ __launch_bounds__(256) void scatter_kernel(
    const float* __restrict__ xw, const float* __restrict__ ew,
    const int* __restrict__ erow, const int* __restrict__ ecol,
    float* __restrict__ out) {
    const int lane = threadIdx.x & 63;
    const int g = lane >> 4;
    const int s = lane & 15;
    const int wave = (int)((blockIdx.x * blockDim.x + threadIdx.x) >> 6);
    const int nwaves = (int)((gridDim.x * (size_t)blockDim.x) >> 6);
    for (int e0 = wave * 4; e0 < N_EDGES; e0 += nwaves * 4) {
        const int e = e0 + g;
        if (e < N_EDGES) {
            const int c = ecol[e];
            const int r = erow[e];
            const float wgt = ew[e];
            const float4 v =
                reinterpret_cast<const float4*>(xw + (size_t)c * FDIM)[s];
            float* dst = out + (size_t)r * FDIM + 4 * s;
            atomicAdd(dst + 0, v.x * wgt);
            atomicAdd(dst + 1, v.y * wgt);
            atomicAdd(dst + 2, v.z * wgt);
            atomicAdd(dst + 3, v.w * wgt);
        }
    }
}

extern "C" void kernel_launch(void* const* d_in, const int* in_sizes, int n_in,
                              void* d_out, int out_size, void* d_ws, size_t ws_size,
                              hipStream_t stream) {
    const float* x  = (const float*)d_in[0];
    const float* w  = (const float*)d_in[1];
    const float* b  = (const float*)d_in[2];
    const float* ew = (const float*)d_in[3];
    const int* erow = (const int*)d_in[4];
    const int* ecol = (const int*)d_in[5];
    float* out = (float*)d_out;

    char* ws = (char*)d_ws;
    const size_t XW_BYTES   = (size_t)N_NODES * FDIM * 4;      // 25.6 MB
    const size_t REC_BYTES  = (size_t)N_EDGES * 8;             // 6.4 MB
    const size_t CNT_BYTES  = (size_t)N_NODES * 4;             // 0.4 MB
    const size_t ST_BYTES   = ((size_t)(N_NODES + 1) * 4 + 15) & ~(size_t)15;
    const size_t SUMS_BYTES = 512;
    const size_t NEED = XW_BYTES + REC_BYTES + CNT_BYTES + ST_BYTES +
                        CNT_BYTES + SUMS_BYTES;                // ~33.6 MB

    float* xw = (float*)ws;   // row-major [N_NODES][64]

    if (ws_size >= NEED) {
        uint2* recs    = (uint2*)(ws + XW_BYTES);
        int* count     = (int*)(ws + XW_BYTES + REC_BYTES);
        int* starts    = (int*)(ws + XW_BYTES + REC_BYTES + CNT_BYTES);
        int* cursor    = (int*)(ws + XW_BYTES + REC_BYTES + CNT_BYTES + ST_BYTES);
        int* blockSums = (int*)(ws + XW_BYTES + REC_BYTES + CNT_BYTES + ST_BYTES + CNT_BYTES);

        const int gE4 = (N_EDGES / 4 + 255) / 256;   // 782
        const int gN  = (N_NODES + 255) / 256 + 1;   // 392 (covers sentinel)

        gemm8_kernel<<<2048, 256, 0, stream>>>(x, w, xw, count);
        hist_kernel<<<gE4, 256, 0, stream>>>(erow, count);
        scan_block_kernel<<<N_SCAN_BLOCKS, SCAN_BLOCK, 0, stream>>>(count, starts, blockSums);
        scanadd_kernel<<<gN, 256, 0, stream>>>(starts, blockSums, cursor);
        fill_kernel<<<gE4, 256, 0, stream>>>(erow, ecol, ew, cursor, recs);
        aggregate_kernel<<<2048, 256, 0, stream>>>(xw, recs, starts, b, out);
    } else {
        gemm_rm_kernel<<<2048, 256, 0, stream>>>(x, w, (float*)ws);
        init_out_kernel<<<2048, 256, 0, stream>>>(out, b);
        scatter_kernel<<<2048, 256, 0, stream>>>((float*)ws, ew, erow, ecol, out);
    }
}

// Round 10
// 203.795 us; speedup vs baseline: 1.6074x; 1.2937x over previous
//
#include <hip/hip_runtime.h>
#include <hip/hip_fp16.h>

#define N_NODES 100000
#define N_EDGES 800000
#define FDIM 64
#define TILE_ROWS 32
#define N_TILES (N_NODES / TILE_ROWS)        // 3125 exactly
#define SCAN_BLOCK 1024
#define N_SCAN_BLOCKS ((N_NODES + SCAN_BLOCK - 1) / SCAN_BLOCK)   // 98

// ---------------------------------------------------------------------------
// Kernel 1: xw(fp16) = x @ w  +  fused degree histogram.
// R8 post-mortem: gemm8 was latency-bound on 128 wave-UNIFORM global x-loads
// per 8-row group (VALUBusy 25%, occ 41%, nothing saturated). Fix: stage the
// x tile in LDS (coalesced float4 loads), read it back as LDS broadcast.
// Also: 1.83M bank conflicts were the quad-transpose staging WRITES; now W is
// read TRANSPOSED from global (4 coalesced dwords/lane) and written as one
// contiguous ds_write_b128 -> conflict-free.
// One block per 32-row tile; 3125 blocks x 256 thr = exactly 800K threads,
// so each thread also does ONE hist atomic (issued first, hides under stage).
// xw stored fp16: halves gemm write traffic + halves aggregate gather bytes.
// ---------------------------------------------------------------------------
__global__ __launch_bounds__(256) void gemm_hist_kernel(
    const float* __restrict__ x, const float* __restrict__ w,
    const int* __restrict__ erow, __half* __restrict__ xwh,
    int* __restrict__ count) {
    const int tid = threadIdx.x;
    const int bid = blockIdx.x;

    // fused histogram: exactly one edge per thread (count pre-zeroed by memset)
    const int e = bid * 256 + tid;
    if (e < N_EDGES) atomicAdd(&count[erow[e]], 1);

    __shared__ float wq[16 * 64 * 4];   // [k0][f][j] = w[4k0+j][f], 16KB
    __shared__ float xs[TILE_ROWS * FDIM];   // 8KB x tile

    const int lane = tid & 63;
    const int wid = tid >> 6;           // wave 0..3

    // stage W transposed: wave w handles k0 = w*4..w*4+3
    float4* wq4 = reinterpret_cast<float4*>(wq);
    #pragma unroll
    for (int it = 0; it < 4; ++it) {
        const int k0 = wid * 4 + it;
        float4 wv;
        wv.x = w[(4 * k0 + 0) * FDIM + lane];   // coalesced 256B per load
        wv.y = w[(4 * k0 + 1) * FDIM + lane];
        wv.z = w[(4 * k0 + 2) * FDIM + lane];
        wv.w = w[(4 * k0 + 3) * FDIM + lane];
        wq4[k0 * 64 + lane] = wv;               // contiguous 1KB wave write
    }

    // stage x tile: 512 float4, 2 per thread, both waves-contiguous
    {
        const float4* xg4 = reinterpret_cast<const float4*>(
            x + (size_t)bid * TILE_ROWS * FDIM);
        float4* xs4 = reinterpret_cast<float4*>(xs);
        xs4[tid] = xg4[tid];
        xs4[256 + tid] = xg4[256 + tid];
    }
    __syncthreads();

    // wave w computes rows w*8..w*8+7 of the tile; lane = feature
    const float4* xs4 = reinterpret_cast<const float4*>(xs);
    const int rbase = wid * 8;
    float acc[8] = {0.f, 0.f, 0.f, 0.f, 0.f, 0.f, 0.f, 0.f};
    #pragma unroll 4
    for (int k0 = 0; k0 < 16; ++k0) {
        const float4 wv = wq4[k0 * 64 + lane];   // 1KB contiguous read
        #pragma unroll
        for (int rr = 0; rr < 8; ++rr) {
            const float4 xv = xs4[(rbase + rr) * 16 + k0];  // LDS broadcast
            acc[rr] += xv.x * wv.x + xv.y * wv.y + xv.z * wv.z + xv.w * wv.w;
        }
    }

    const int growbase = bid * TILE_ROWS + rbase;
    #pragma unroll
    for (int rr = 0; rr < 8; ++rr)
        xwh[(size_t)(growbase + rr) * FDIM + lane] = __float2half(acc[rr]);
}

// ---------------------------------------------------------------------------
// Kernel 2: per-1024-block scan -> block-local exclusive starts + block sums
// ---------------------------------------------------------------------------
__global__ __launch_bounds__(SCAN_BLOCK) void scan_block_kernel(
    const int* __restrict__ count, int* __restrict__ starts,
    int* __restrict__ blockSums) {
    __shared__ int tmp[SCAN_BLOCK];
    const int tid = threadIdx.x;
    const int i = blockIdx.x * SCAN_BLOCK + tid;
    const int v = (i < N_NODES) ? count[i] : 0;
    tmp[tid] = v;
    __syncthreads();
    for (int off = 1; off < SCAN_BLOCK; off <<= 1) {
        int t = (tid >= off) ? tmp[tid - off] : 0;
        __syncthreads();
        tmp[tid] += t;
        __syncthreads();
    }
    if (i < N_NODES) starts[i] = tmp[tid] - v;
    if (tid == SCAN_BLOCK - 1) blockSums[blockIdx.x] = tmp[tid];
}

// ---------------------------------------------------------------------------
// Kernel 3: redundant block-sum scan in LDS + offset add + sentinel.
// ---------------------------------------------------------------------------
__global__ __launch_bounds__(256) void scanadd_kernel(
    int* __restrict__ starts, const int* __restrict__ blockSums,
    int* __restrict__ cursor) {
    __shared__ int ssum[128];
    const int tid = threadIdx.x;
    if (tid < 128) ssum[tid] = (tid < N_SCAN_BLOCKS) ? blockSums[tid] : 0;
    __syncthreads();
    for (int off = 1; off < 128; off <<= 1) {
        int t = (tid < 128 && tid >= off) ? ssum[tid - off] : 0;
        __syncthreads();
        if (tid < 128) ssum[tid] += t;   // inclusive
        __syncthreads();
    }
    const int i = blockIdx.x * 256 + tid;
    if (i < N_NODES) {
        const int j = i >> 10;
        const int add = (j == 0) ? 0 : ssum[j - 1];
        const int s = starts[i] + add;
        starts[i] = s;
        cursor[i] = s;
    } else if (i == N_NODES) {
        starts[N_NODES] = N_EDGES;
    }
}

// ---------------------------------------------------------------------------
// Kernel 4: bucket fill -> packed (col, weight_bits) 8B records.
// 4 edges/thread, 4 atomics in flight.
// ---------------------------------------------------------------------------
__global__ __launch_bounds__(256) void fill_kernel(
    const int* __restrict__ erow, const int* __restrict__ ecol,
    const float* __restrict__ ew, int* __restrict__ cursor,
    uint2* __restrict__ recs) {
    const int base = (blockIdx.x * 256 + threadIdx.x) * 4;
    if (base + 3 < N_EDGES) {
        int4 r = *reinterpret_cast<const int4*>(erow + base);
        int4 c = *reinterpret_cast<const int4*>(ecol + base);
        float4 wt = *reinterpret_cast<const float4*>(ew + base);
        int p0 = atomicAdd(&cursor[r.x], 1);
        int p1 = atomicAdd(&cursor[r.y], 1);
        int p2 = atomicAdd(&cursor[r.z], 1);
        int p3 = atomicAdd(&cursor[r.w], 1);
        recs[p0] = make_uint2((unsigned)c.x, __float_as_uint(wt.x));
        recs[p1] = make_uint2((unsigned)c.y, __float_as_uint(wt.y));
        recs[p2] = make_uint2((unsigned)c.z, __float_as_uint(wt.z));
        recs[p3] = make_uint2((unsigned)c.w, __float_as_uint(wt.w));
    } else {
        for (int e = base; e < N_EDGES; ++e) {
            int p = atomicAdd(&cursor[erow[e]], 1);
            recs[p] = make_uint2((unsigned)ecol[e], __float_as_uint(ew[e]));
        }
    }
}

// ---------------------------------------------------------------------------
// Kernel 5: aggregate from fp16 xw. 16 lanes/row (lane s holds features
// 4s..4s+3), gather = 8B/lane -> 128B/edge (was 256B). Measured floor was
// the 165.8MB L2-miss stream at 2.5 TB/s; halving gather bytes halves it.
// f32 accumulate; x4 unroll for gather MLP; recs nontemporal (stream-once).
// ---------------------------------------------------------------------------
__global__ __launch_bounds__(256) void aggregate_h_kernel(
    const __half* __restrict__ xwh, const uint2* __restrict__ recs,
    const int* __restrict__ starts, const float* __restrict__ b,
    float* __restrict__ out) {
    const int lane = threadIdx.x & 63;
    const int g = lane >> 4;        // row slot within wave
    const int s = lane & 15;        // feature quad
    const int wave = (int)((blockIdx.x * blockDim.x + threadIdx.x) >> 6);
    const int nwaves = (int)((gridDim.x * (size_t)blockDim.x) >> 6);
    const float4 bias = reinterpret_cast<const float4*>(b)[s];
    const unsigned long long* recs8 =
        reinterpret_cast<const unsigned long long*>(recs);

    for (int r0 = wave * 4; r0 < N_NODES; r0 += nwaves * 4) {
        const int r = r0 + g;
        if (r < N_NODES) {
            const int st = starts[r];
            const int cnt = starts[r + 1] - st;
            float4 acc = bias;
            int k = 0;
            for (; k + 4 <= cnt; k += 4) {
                unsigned long long p0 = __builtin_nontemporal_load(recs8 + st + k + 0);
                unsigned long long p1 = __builtin_nontemporal_load(recs8 + st + k + 1);
                unsigned long long p2 = __builtin_nontemporal_load(recs8 + st + k + 2);
                unsigned long long p3 = __builtin_nontemporal_load(recs8 + st + k + 3);
                uint2 g0 = *reinterpret_cast<const uint2*>(
                    xwh + (size_t)(unsigned)p0 * FDIM + 4 * s);
                uint2 g1 = *reinterpret_cast<const uint2*>(
                    xwh + (size_t)(unsigned)p1 * FDIM + 4 * s);
                uint2 g2 = *reinterpret_cast<const uint2*>(
                    xwh + (size_t)(unsigned)p2 * FDIM + 4 * s);
                uint2 g3 = *reinterpret_cast<const uint2*>(
                    xwh + (size_t)(unsigned)p3 * FDIM + 4 * s);
                const float w0 = __uint_as_float((unsigned)(p0 >> 32));
                const float w1 = __uint_as_float((unsigned)(p1 >> 32));
                const float w2 = __uint_as_float((unsigned)(p2 >> 32));
                const float w3 = __uint_as_float((unsigned)(p3 >> 32));
                float2 a0 = __half22float2(*reinterpret_cast<__half2*>(&g0.x));
                float2 b0 = __half22float2(*reinterpret_cast<__half2*>(&g0.y));
                float2 a1 = __half22float2(*reinterpret_cast<__half2*>(&g1.x));
                float2 b1 = __half22float2(*reinterpret_cast<__half2*>(&g1.y));
                float2 a2 = __half22float2(*reinterpret_cast<__half2*>(&g2.x));
                float2 b2 = __half22float2(*reinterpret_cast<__half2*>(&g2.y));
                float2 a3 = __half22float2(*reinterpret_cast<__half2*>(&g3.x));
                float2 b3 = __half22float2(*reinterpret_cast<__half2*>(&g3.y));
                acc.x += a0.x * w0 + a1.x * w1 + a2.x * w2 + a3.x * w3;
                acc.y += a0.y * w0 + a1.y * w1 + a2.y * w2 + a3.y * w3;
                acc.z += b0.x * w0 + b1.x * w1 + b2.x * w2 + b3.x * w3;
                acc.w += b0.y * w0 + b1.y * w1 + b2.y * w2 + b3.y * w3;
            }
            for (; k < cnt; ++k) {
                unsigned long long p0 = __builtin_nontemporal_load(recs8 + st + k);
                uint2 g0 = *reinterpret_cast<const uint2*>(
                    xwh + (size_t)(unsigned)p0 * FDIM + 4 * s);
                const float w0 = __uint_as_float((unsigned)(p0 >> 32));
                float2 a0 = __half22float2(*reinterpret_cast<__half2*>(&g0.x));
                float2 b0 = __half22float2(*reinterpret_cast<__half2*>(&g0.y));
                acc.x += a0.x * w0; acc.y += a0.y * w0;
                acc.z += b0.x * w0; acc.w += b0.y * w0;
            }
            reinterpret_cast<float4*>(out + (size_t)r * FDIM)[s] = acc;
        }
    }
}

// --------------------------- atomic fallback (unused in practice) ----------
__global__ __launch_bounds__(256) void gemm_rm_kernel(
    const float* __restrict__ x, const float* __restrict__ w,
    float* __restrict__ xw) {
    const int lane = threadIdx.x & 63;
    float wr[FDIM];
    #pragma unroll
    for (int k = 0; k < FDIM; ++k) wr[k] = w[k * FDIM + lane];
    const int gwave = blockIdx.x * 4 + (threadIdx.x >> 6);
    const int nwaves = gridDim.x * 4;
    for (int row = gwave; row < N_NODES; row += nwaves) {
        const float4* xr = reinterpret_cast<const float4*>(x + (size_t)row * FDIM);
        float a0 = 0.f, a1 = 0.f, a2 = 0.f, a3 = 0.f;
        #pragma unroll
        for (int k0 = 0; k0 < FDIM / 4; ++k0) {
            float4 xv = xr[k0];
            a0 += xv.x * wr[4 * k0 + 0];
            a1 += xv.y * wr[4 * k0 + 1];
            a2 += xv.z * wr[4 * k0 + 2];
            a3 += xv.w * wr[4 * k0 + 3];
        }
        xw[(size_t)row * FDIM + lane] = (a0 + a1) + (a2 + a3);
    }
}

__global__ __launch_bounds__(256) void init_out_kernel(
    float* __restrict__ out, const float* __restrict__ b) {
    const float4* b4 = reinterpret_cast<const float4*>(b);
    float4* out4 = reinterpret_cast<float4*>(out);
    const size_t total = (size_t)N_NODES * FDIM / 4;
    size_t i = (size_t)blockIdx.x * blockDim.x + threadIdx.x;
    const size_t stride = (size_t)gridDim.x * blockDim.x;
    for (; i < total; i += stride) out4[i] = b4[i & 15];
}

__global__ __launch_bounds__(256) void scatter_kernel(
    const float* __restrict__ xw, const float* __restrict__ ew,
    const int* __restrict__ erow, const int* __restrict__ ecol,
    float* __restrict__ out) {
    const int lane = threadIdx.x & 63;
    const int g = lane >> 4;
    const int s = lane & 15;
    const int wave = (int)((blockIdx.x * blockDim.x + threadIdx.x) >> 6);
    const int nwaves = (int)((gridDim.x * (size_t)blockDim.x) >> 6);
    for (int e0 = wave * 4; e0 < N_EDGES; e0 += nwaves * 4) {
        const int e = e0 + g;
        if (e < N_EDGES) {
            const int c = ecol[e];
            const int r = erow[e];
            const float wgt = ew[e];
            const float4 v =
                reinterpret_cast<const float4*>(xw + (size_t)c * FDIM)[s];
            float* dst = out + (size_t)r * FDIM + 4 * s;
            atomicAdd(dst + 0, v.x * wgt);
            atomicAdd(dst + 1, v.y * wgt);
            atomicAdd(dst + 2, v.z * wgt);
            atomicAdd(dst + 3, v.w * wgt);
        }
    }
}

extern "C" void kernel_launch(void* const* d_in, const int* in_sizes, int n_in,
                              void* d_out, int out_size, void* d_ws, size_t ws_size,
                              hipStream_t stream) {
    const float* x  = (const float*)d_in[0];
    const float* w  = (const float*)d_in[1];
    const float* b  = (const float*)d_in[2];
    const float* ew = (const float*)d_in[3];
    const int* erow = (const int*)d_in[4];
    const int* ecol = (const int*)d_in[5];
    float* out = (float*)d_out;

    char* ws = (char*)d_ws;
    const size_t XWH_BYTES  = (size_t)N_NODES * FDIM * 2;      // 12.8 MB fp16
    const size_t REC_BYTES  = (size_t)N_EDGES * 8;             // 6.4 MB
    const size_t CNT_BYTES  = (size_t)N_NODES * 4;             // 0.4 MB
    const size_t ST_BYTES   = ((size_t)(N_NODES + 1) * 4 + 15) & ~(size_t)15;
    const size_t SUMS_BYTES = 512;
    const size_t NEED = XWH_BYTES + REC_BYTES + CNT_BYTES + ST_BYTES +
                        CNT_BYTES + SUMS_BYTES;                // ~20.9 MB

    if (ws_size >= NEED) {
        __half* xwh    = (__half*)ws;
        uint2* recs    = (uint2*)(ws + XWH_BYTES);
        int* count     = (int*)(ws + XWH_BYTES + REC_BYTES);
        int* starts    = (int*)(ws + XWH_BYTES + REC_BYTES + CNT_BYTES);
        int* cursor    = (int*)(ws + XWH_BYTES + REC_BYTES + CNT_BYTES + ST_BYTES);
        int* blockSums = (int*)(ws + XWH_BYTES + REC_BYTES + CNT_BYTES + ST_BYTES + CNT_BYTES);

        const int gE4 = (N_EDGES / 4 + 255) / 256;   // 782
        const int gN  = (N_NODES + 255) / 256 + 1;   // 392 (covers sentinel)

        hipMemsetAsync(count, 0, CNT_BYTES, stream);            // zero degrees
        gemm_hist_kernel<<<N_TILES, 256, 0, stream>>>(x, w, erow, xwh, count);
        scan_block_kernel<<<N_SCAN_BLOCKS, SCAN_BLOCK, 0, stream>>>(count, starts, blockSums);
        scanadd_kernel<<<gN, 256, 0, stream>>>(starts, blockSums, cursor);
        fill_kernel<<<gE4, 256, 0, stream>>>(erow, ecol, ew, cursor, recs);
        aggregate_h_kernel<<<2048, 256, 0, stream>>>(xwh, recs, starts, b, out);
    } else {
        // fallback: f32 xw + atomic scatter (needs 25.6 MB)
        float* xw = (float*)ws;
        gemm_rm_kernel<<<2048, 256, 0, stream>>>(x, w, xw);
        init_out_kernel<<<2048, 256, 0, stream>>>(out, b);
        scatter_kernel<<<2048, 256, 0, stream>>>(xw, ew, erow, ecol, out);
    }
}

// Round 13
// 197.654 us; speedup vs baseline: 1.6573x; 1.0311x over previous
//
#include <hip/hip_runtime.h>
#include <hip/hip_fp16.h>

#define N_NODES 100000
#define N_EDGES 800000
#define FDIM 64
#define TILE_ROWS 32
#define N_TILES (N_NODES / TILE_ROWS)        // 3125 exactly
#define SCAN_BLOCK 1024
#define N_SCAN_BLOCKS ((N_NODES + SCAN_BLOCK - 1) / SCAN_BLOCK)   // 98

typedef int   iv4 __attribute__((ext_vector_type(4)));
typedef float fv4 __attribute__((ext_vector_type(4)));

// ---------------------------------------------------------------------------
// Kernel 1: xw(fp16) = x @ w  +  fused degree histogram.  (UNCHANGED from R8
// measured config: dropped out of top-5, i.e. < 57us.)
// ---------------------------------------------------------------------------
__global__ __launch_bounds__(256) void gemm_hist_kernel(
    const float* __restrict__ x, const float* __restrict__ w,
    const int* __restrict__ erow, __half* __restrict__ xwh,
    int* __restrict__ count) {
    const int tid = threadIdx.x;
    const int bid = blockIdx.x;

    // fused histogram: exactly one edge per thread (count pre-zeroed by memset)
    const int e = bid * 256 + tid;
    if (e < N_EDGES) atomicAdd(&count[erow[e]], 1);

    __shared__ float wq[16 * 64 * 4];        // [k0][f][j] = w[4k0+j][f], 16KB
    __shared__ float xs[TILE_ROWS * FDIM];   // 8KB x tile

    const int lane = tid & 63;
    const int wid = tid >> 6;                // wave 0..3

    // stage W transposed: wave w handles k0 = w*4..w*4+3
    float4* wq4 = reinterpret_cast<float4*>(wq);
    #pragma unroll
    for (int it = 0; it < 4; ++it) {
        const int k0 = wid * 4 + it;
        float4 wv;
        wv.x = w[(4 * k0 + 0) * FDIM + lane];   // coalesced 256B per load
        wv.y = w[(4 * k0 + 1) * FDIM + lane];
        wv.z = w[(4 * k0 + 2) * FDIM + lane];
        wv.w = w[(4 * k0 + 3) * FDIM + lane];
        wq4[k0 * 64 + lane] = wv;               // contiguous 1KB wave write
    }

    // stage x tile: 512 float4, 2 per thread
    {
        const float4* xg4 = reinterpret_cast<const float4*>(
            x + (size_t)bid * TILE_ROWS * FDIM);
        float4* xs4 = reinterpret_cast<float4*>(xs);
        xs4[tid] = xg4[tid];
        xs4[256 + tid] = xg4[256 + tid];
    }
    __syncthreads();

    // wave w computes rows w*8..w*8+7 of the tile; lane = feature
    const float4* xs4 = reinterpret_cast<const float4*>(xs);
    const int rbase = wid * 8;
    float acc[8] = {0.f, 0.f, 0.f, 0.f, 0.f, 0.f, 0.f, 0.f};
    #pragma unroll 4
    for (int k0 = 0; k0 < 16; ++k0) {
        const float4 wv = wq4[k0 * 64 + lane];   // contiguous read
        #pragma unroll
        for (int rr = 0; rr < 8; ++rr) {
            const float4 xv = xs4[(rbase + rr) * 16 + k0];  // LDS broadcast
            acc[rr] += xv.x * wv.x + xv.y * wv.y + xv.z * wv.z + xv.w * wv.w;
        }
    }

    const int growbase = bid * TILE_ROWS + rbase;
    #pragma unroll
    for (int rr = 0; rr < 8; ++rr)
        xwh[(size_t)(growbase + rr) * FDIM + lane] = __float2half(acc[rr]);
}

// ---------------------------------------------------------------------------
// Kernel 2: per-1024-block scan -> block-local exclusive starts + block sums
// ---------------------------------------------------------------------------
__global__ __launch_bounds__(SCAN_BLOCK) void scan_block_kernel(
    const int* __restrict__ count, int* __restrict__ starts,
    int* __restrict__ blockSums) {
    __shared__ int tmp[SCAN_BLOCK];
    const int tid = threadIdx.x;
    const int i = blockIdx.x * SCAN_BLOCK + tid;
    const int v = (i < N_NODES) ? count[i] : 0;
    tmp[tid] = v;
    __syncthreads();
    for (int off = 1; off < SCAN_BLOCK; off <<= 1) {
        int t = (tid >= off) ? tmp[tid - off] : 0;
        __syncthreads();
        tmp[tid] += t;
        __syncthreads();
    }
    if (i < N_NODES) starts[i] = tmp[tid] - v;
    if (tid == SCAN_BLOCK - 1) blockSums[blockIdx.x] = tmp[tid];
}

// ---------------------------------------------------------------------------
// Kernel 3: redundant block-sum scan in LDS + offset add + sentinel.
// ---------------------------------------------------------------------------
__global__ __launch_bounds__(256) void scanadd_kernel(
    int* __restrict__ starts, const int* __restrict__ blockSums,
    int* __restrict__ cursor) {
    __shared__ int ssum[128];
    const int tid = threadIdx.x;
    if (tid < 128) ssum[tid] = (tid < N_SCAN_BLOCKS) ? blockSums[tid] : 0;
    __syncthreads();
    for (int off = 1; off < 128; off <<= 1) {
        int t = (tid < 128 && tid >= off) ? ssum[tid - off] : 0;
        __syncthreads();
        if (tid < 128) ssum[tid] += t;   // inclusive
        __syncthreads();
    }
    const int i = blockIdx.x * 256 + tid;
    if (i < N_NODES) {
        const int j = i >> 10;
        const int add = (j == 0) ? 0 : ssum[j - 1];
        const int s = starts[i] + add;
        starts[i] = s;
        cursor[i] = s;
    } else if (i == N_NODES) {
        starts[N_NODES] = N_EDGES;
    }
}

// ---------------------------------------------------------------------------
// Kernel 4: XCD-PARTITIONED bucket fill. R10 post-mortem: old fill wrote
// 53.4MB for 6.4MB of records — each row's ~64B bucket line was written by
// 8 threads on RANDOM XCDs, so the line bounced between per-XCD L2s (one
// partial-line transaction per 8B write). Fix: 8x blocks; block b runs on
// XCD b&7 (consecutive blockIdx round-robin XCDs, m09) and processes ONLY
// edges with erow&7 == b&7 -> all writes to a row's line come from ONE XCD,
// the line composes in that L2 and evicts once. Edge streams re-read 8x
// (L3-resident, nontemporal so they don't evict partial recs lines).
// Cursor atomics also become XCD-local.
// PREDICT: WRITE_SIZE 53.4 -> ~12MB, dur 58 -> 15-25us.
// ---------------------------------------------------------------------------
__global__ __launch_bounds__(256) void fill_xcd_kernel(
    const int* __restrict__ erow, const int* __restrict__ ecol,
    const float* __restrict__ ew, int* __restrict__ cursor,
    uint2* __restrict__ recs) {
    const int xcd = blockIdx.x & 7;          // XCD this block lands on (m09)
    const int chunk = blockIdx.x >> 3;       // edge chunk, same range as before
    const int base = (chunk * 256 + threadIdx.x) * 4;
    if (base + 3 < N_EDGES) {
        iv4 r = __builtin_nontemporal_load(
            reinterpret_cast<const iv4*>(erow + base));
        iv4 c = __builtin_nontemporal_load(
            reinterpret_cast<const iv4*>(ecol + base));
        fv4 wt = __builtin_nontemporal_load(
            reinterpret_cast<const fv4*>(ew + base));
        #pragma unroll
        for (int j = 0; j < 4; ++j) {
            const int rr = r[j];
            if ((rr & 7) == xcd) {           // ~1/8 lanes active per j
                const int p = atomicAdd(&cursor[rr], 1);
                recs[p] = make_uint2((unsigned)c[j], __float_as_uint(wt[j]));
            }
        }
    } else {
        for (int e = base; e < N_EDGES; ++e) {
            const int rr = erow[e];
            if ((rr & 7) == xcd) {
                const int p = atomicAdd(&cursor[rr], 1);
                recs[p] = make_uint2((unsigned)ecol[e], __float_as_uint(ew[e]));
            }
        }
    }
}

// ---------------------------------------------------------------------------
// Kernel 5: aggregate from fp16 xw. (UNCHANGED from R10 measured config:
// dropped out of top-5 after fp16 halved the gather stream.)
// ---------------------------------------------------------------------------
__global__ __launch_bounds__(256) void aggregate_h_kernel(
    const __half* __restrict__ xwh, const uint2* __restrict__ recs,
    const int* __restrict__ starts, const float* __restrict__ b,
    float* __restrict__ out) {
    const int lane = threadIdx.x & 63;
    const int g = lane >> 4;        // row slot within wave
    const int s = lane & 15;        // feature quad
    const int wave = (int)((blockIdx.x * blockDim.x + threadIdx.x) >> 6);
    const int nwaves = (int)((gridDim.x * (size_t)blockDim.x) >> 6);
    const float4 bias = reinterpret_cast<const float4*>(b)[s];
    const unsigned long long* recs8 =
        reinterpret_cast<const unsigned long long*>(recs);

    for (int r0 = wave * 4; r0 < N_NODES; r0 += nwaves * 4) {
        const int r = r0 + g;
        if (r < N_NODES) {
            const int st = starts[r];
            const int cnt = starts[r + 1] - st;
            float4 acc = bias;
            int k = 0;
            for (; k + 4 <= cnt; k += 4) {
                unsigned long long p0 = __builtin_nontemporal_load(recs8 + st + k + 0);
                unsigned long long p1 = __builtin_nontemporal_load(recs8 + st + k + 1);
                unsigned long long p2 = __builtin_nontemporal_load(recs8 + st + k + 2);
                unsigned long long p3 = __builtin_nontemporal_load(recs8 + st + k + 3);
                uint2 g0 = *reinterpret_cast<const uint2*>(
                    xwh + (size_t)(unsigned)p0 * FDIM + 4 * s);
                uint2 g1 = *reinterpret_cast<const uint2*>(
                    xwh + (size_t)(unsigned)p1 * FDIM + 4 * s);
                uint2 g2 = *reinterpret_cast<const uint2*>(
                    xwh + (size_t)(unsigned)p2 * FDIM + 4 * s);
                uint2 g3 = *reinterpret_cast<const uint2*>(
                    xwh + (size_t)(unsigned)p3 * FDIM + 4 * s);
                const float w0 = __uint_as_float((unsigned)(p0 >> 32));
                const float w1 = __uint_as_float((unsigned)(p1 >> 32));
                const float w2 = __uint_as_float((unsigned)(p2 >> 32));
                const float w3 = __uint_as_float((unsigned)(p3 >> 32));
                float2 a0 = __half22float2(*reinterpret_cast<__half2*>(&g0.x));
                float2 b0 = __half22float2(*reinterpret_cast<__half2*>(&g0.y));
                float2 a1 = __half22float2(*reinterpret_cast<__half2*>(&g1.x));
                float2 b1 = __half22float2(*reinterpret_cast<__half2*>(&g1.y));
                float2 a2 = __half22float2(*reinterpret_cast<__half2*>(&g2.x));
                float2 b2 = __half22float2(*reinterpret_cast<__half2*>(&g2.y));
                float2 a3 = __half22float2(*reinterpret_cast<__half2*>(&g3.x));
                float2 b3 = __half22float2(*reinterpret_cast<__half2*>(&g3.y));
                acc.x += a0.x * w0 + a1.x * w1 + a2.x * w2 + a3.x * w3;
                acc.y += a0.y * w0 + a1.y * w1 + a2.y * w2 + a3.y * w3;
                acc.z += b0.x * w0 + b1.x * w1 + b2.x * w2 + b3.x * w3;
                acc.w += b0.y * w0 + b1.y * w1 + b2.y * w2 + b3.y * w3;
            }
            for (; k < cnt; ++k) {
                unsigned long long p0 = __builtin_nontemporal_load(recs8 + st + k);
                uint2 g0 = *reinterpret_cast<const uint2*>(
                    xwh + (size_t)(unsigned)p0 * FDIM + 4 * s);
                const float w0 = __uint_as_float((unsigned)(p0 >> 32));
                float2 a0 = __half22float2(*reinterpret_cast<__half2*>(&g0.x));
                float2 b0 = __half22float2(*reinterpret_cast<__half2*>(&g0.y));
                acc.x += a0.x * w0; acc.y += a0.y * w0;
                acc.z += b0.x * w0; acc.w += b0.y * w0;
            }
            reinterpret_cast<float4*>(out + (size_t)r * FDIM)[s] = acc;
        }
    }
}

// --------------------------- atomic fallback (unused in practice) ----------
__global__ __launch_bounds__(256) void gemm_rm_kernel(
    const float* __restrict__ x, const float* __restrict__ w,
    float* __restrict__ xw) {
    const int lane = threadIdx.x & 63;
    float wr[FDIM];
    #pragma unroll
    for (int k = 0; k < FDIM; ++k) wr[k] = w[k * FDIM + lane];
    const int gwave = blockIdx.x * 4 + (threadIdx.x >> 6);
    const int nwaves = gridDim.x * 4;
    for (int row = gwave; row < N_NODES; row += nwaves) {
        const float4* xr = reinterpret_cast<const float4*>(x + (size_t)row * FDIM);
        float a0 = 0.f, a1 = 0.f, a2 = 0.f, a3 = 0.f;
        #pragma unroll
        for (int k0 = 0; k0 < FDIM / 4; ++k0) {
            float4 xv = xr[k0];
            a0 += xv.x * wr[4 * k0 + 0];
            a1 += xv.y * wr[4 * k0 + 1];
            a2 += xv.z * wr[4 * k0 + 2];
            a3 += xv.w * wr[4 * k0 + 3];
        }
        xw[(size_t)row * FDIM + lane] = (a0 + a1) + (a2 + a3);
    }
}

__global__ __launch_bounds__(256) void init_out_kernel(
    float* __restrict__ out, const float* __restrict__ b) {
    const float4* b4 = reinterpret_cast<const float4*>(b);
    float4* out4 = reinterpret_cast<float4*>(out);
    const size_t total = (size_t)N_NODES * FDIM / 4;
    size_t i = (size_t)blockIdx.x * blockDim.x + threadIdx.x;
    const size_t stride = (size_t)gridDim.x * blockDim.x;
    for (; i < total; i += stride) out4[i] = b4[i & 15];
}

__global__ __launch_bounds__(256) void scatter_kernel(
    const float* __restrict__ xw, const float* __restrict__ ew,
    const int* __restrict__ erow, const int* __restrict__ ecol,
    float* __restrict__ out) {
    const int lane = threadIdx.x & 63;
    const int g = lane >> 4;
    const int s = lane & 15;
    const int wave = (int)((blockIdx.x * blockDim.x + threadIdx.x) >> 6);
    const int nwaves = (int)((gridDim.x * (size_t)blockDim.x) >> 6);
    for (int e0 = wave * 4; e0 < N_EDGES; e0 += nwaves * 4) {
        const int e = e0 + g;
        if (e < N_EDGES) {
            const int c = ecol[e];
            const int r = erow[e];
            const float wgt = ew[e];
            const float4 v =
                reinterpret_cast<const float4*>(xw + (size_t)c * FDIM)[s];
            float* dst = out + (size_t)r * FDIM + 4 * s;
            atomicAdd(dst + 0, v.x * wgt);
            atomicAdd(dst + 1, v.y * wgt);
            atomicAdd(dst + 2, v.z * wgt);
            atomicAdd(dst + 3, v.w * wgt);
        }
    }
}

extern "C" void kernel_launch(void* const* d_in, const int* in_sizes, int n_in,
                              void* d_out, int out_size, void* d_ws, size_t ws_size,
                              hipStream_t stream) {
    const float* x  = (const float*)d_in[0];
    const float* w  = (const float*)d_in[1];
    const float* b  = (const float*)d_in[2];
    const float* ew = (const float*)d_in[3];
    const int* erow = (const int*)d_in[4];
    const int* ecol = (const int*)d_in[5];
    float* out = (float*)d_out;

    char* ws = (char*)d_ws;
    const size_t XWH_BYTES  = (size_t)N_NODES * FDIM * 2;      // 12.8 MB fp16
    const size_t REC_BYTES  = (size_t)N_EDGES * 8;             // 6.4 MB
    const size_t CNT_BYTES  = (size_t)N_NODES * 4;             // 0.4 MB
    const size_t ST_BYTES   = ((size_t)(N_NODES + 1) * 4 + 15) & ~(size_t)15;
    const size_t SUMS_BYTES = 512;
    const size_t NEED = XWH_BYTES + REC_BYTES + CNT_BYTES + ST_BYTES +
                        CNT_BYTES + SUMS_BYTES;                // ~20.9 MB

    if (ws_size >= NEED) {
        __half* xwh    = (__half*)ws;
        uint2* recs    = (uint2*)(ws + XWH_BYTES);
        int* count     = (int*)(ws + XWH_BYTES + REC_BYTES);
        int* starts    = (int*)(ws + XWH_BYTES + REC_BYTES + CNT_BYTES);
        int* cursor    = (int*)(ws + XWH_BYTES + REC_BYTES + CNT_BYTES + ST_BYTES);
        int* blockSums = (int*)(ws + XWH_BYTES + REC_BYTES + CNT_BYTES + ST_BYTES + CNT_BYTES);

        const int gE4 = (N_EDGES / 4 + 255) / 256;   // 782
        const int gN  = (N_NODES + 255) / 256 + 1;   // 392 (covers sentinel)

        hipMemsetAsync(count, 0, CNT_BYTES, stream);            // zero degrees
        gemm_hist_kernel<<<N_TILES, 256, 0, stream>>>(x, w, erow, xwh, count);
        scan_block_kernel<<<N_SCAN_BLOCKS, SCAN_BLOCK, 0, stream>>>(count, starts, blockSums);
        scanadd_kernel<<<gN, 256, 0, stream>>>(starts, blockSums, cursor);
        fill_xcd_kernel<<<gE4 * 8, 256, 0, stream>>>(erow, ecol, ew, cursor, recs);
        aggregate_h_kernel<<<2048, 256, 0, stream>>>(xwh, recs, starts, b, out);
    } else {
        // fallback: f32 xw + atomic scatter (needs 25.6 MB)
        float* xw = (float*)ws;
        gemm_rm_kernel<<<2048, 256, 0, stream>>>(x, w, xw);
        init_out_kernel<<<2048, 256, 0, stream>>>(out, b);
        scatter_kernel<<<2048, 256, 0, stream>>>(xw, ew, erow, ecol, out);
    }
}

// Round 15
// 194.718 us; speedup vs baseline: 1.6823x; 1.0151x over previous
//
#include <hip/hip_runtime.h>
#include <hip/hip_fp16.h>

#define N_NODES 100000
#define N_EDGES 800000
#define FDIM 64
#define TILE_ROWS 32
#define N_TILES (N_NODES / TILE_ROWS)        // 3125 exactly
#define SCAN_BLOCK 1024
#define N_SCAN_BLOCKS ((N_NODES + SCAN_BLOCK - 1) / SCAN_BLOCK)   // 98
#define ROWS_PER_XCD (N_NODES / 8)           // 12500 exactly

typedef int   iv4 __attribute__((ext_vector_type(4)));
typedef float fv4 __attribute__((ext_vector_type(4)));

// ---------------------------------------------------------------------------
// Kernel 1: xw(fp16) = x @ w  +  fused degree histogram. (UNCHANGED; below
// top-5 cutoff since R10.)
// ---------------------------------------------------------------------------
__global__ __launch_bounds__(256) void gemm_hist_kernel(
    const float* __restrict__ x, const float* __restrict__ w,
    const int* __restrict__ erow, __half* __restrict__ xwh,
    int* __restrict__ count) {
    const int tid = threadIdx.x;
    const int bid = blockIdx.x;

    // fused histogram: exactly one edge per thread (count pre-zeroed by memset)
    const int e = bid * 256 + tid;
    if (e < N_EDGES) atomicAdd(&count[erow[e]], 1);

    __shared__ float wq[16 * 64 * 4];        // [k0][f][j] = w[4k0+j][f], 16KB
    __shared__ float xs[TILE_ROWS * FDIM];   // 8KB x tile

    const int lane = tid & 63;
    const int wid = tid >> 6;                // wave 0..3

    // stage W transposed: wave w handles k0 = w*4..w*4+3
    float4* wq4 = reinterpret_cast<float4*>(wq);
    #pragma unroll
    for (int it = 0; it < 4; ++it) {
        const int k0 = wid * 4 + it;
        float4 wv;
        wv.x = w[(4 * k0 + 0) * FDIM + lane];   // coalesced 256B per load
        wv.y = w[(4 * k0 + 1) * FDIM + lane];
        wv.z = w[(4 * k0 + 2) * FDIM + lane];
        wv.w = w[(4 * k0 + 3) * FDIM + lane];
        wq4[k0 * 64 + lane] = wv;               // contiguous 1KB wave write
    }

    // stage x tile: 512 float4, 2 per thread
    {
        const float4* xg4 = reinterpret_cast<const float4*>(
            x + (size_t)bid * TILE_ROWS * FDIM);
        float4* xs4 = reinterpret_cast<float4*>(xs);
        xs4[tid] = xg4[tid];
        xs4[256 + tid] = xg4[256 + tid];
    }
    __syncthreads();

    // wave w computes rows w*8..w*8+7 of the tile; lane = feature
    const float4* xs4 = reinterpret_cast<const float4*>(xs);
    const int rbase = wid * 8;
    float acc[8] = {0.f, 0.f, 0.f, 0.f, 0.f, 0.f, 0.f, 0.f};
    #pragma unroll 4
    for (int k0 = 0; k0 < 16; ++k0) {
        const float4 wv = wq4[k0 * 64 + lane];   // contiguous read
        #pragma unroll
        for (int rr = 0; rr < 8; ++rr) {
            const float4 xv = xs4[(rbase + rr) * 16 + k0];  // LDS broadcast
            acc[rr] += xv.x * wv.x + xv.y * wv.y + xv.z * wv.z + xv.w * wv.w;
        }
    }

    const int growbase = bid * TILE_ROWS + rbase;
    #pragma unroll
    for (int rr = 0; rr < 8; ++rr)
        xwh[(size_t)(growbase + rr) * FDIM + lane] = __float2half(acc[rr]);
}

// ---------------------------------------------------------------------------
// Kernel 2: per-1024-block scan -> block-local exclusive starts + block sums
// ---------------------------------------------------------------------------
__global__ __launch_bounds__(SCAN_BLOCK) void scan_block_kernel(
    const int* __restrict__ count, int* __restrict__ starts,
    int* __restrict__ blockSums) {
    __shared__ int tmp[SCAN_BLOCK];
    const int tid = threadIdx.x;
    const int i = blockIdx.x * SCAN_BLOCK + tid;
    const int v = (i < N_NODES) ? count[i] : 0;
    tmp[tid] = v;
    __syncthreads();
    for (int off = 1; off < SCAN_BLOCK; off <<= 1) {
        int t = (tid >= off) ? tmp[tid - off] : 0;
        __syncthreads();
        tmp[tid] += t;
        __syncthreads();
    }
    if (i < N_NODES) starts[i] = tmp[tid] - v;
    if (tid == SCAN_BLOCK - 1) blockSums[blockIdx.x] = tmp[tid];
}

// ---------------------------------------------------------------------------
// Kernel 3: redundant block-sum scan in LDS + offset add + sentinel.
// ---------------------------------------------------------------------------
__global__ __launch_bounds__(256) void scanadd_kernel(
    int* __restrict__ starts, const int* __restrict__ blockSums,
    int* __restrict__ cursor) {
    __shared__ int ssum[128];
    const int tid = threadIdx.x;
    if (tid < 128) ssum[tid] = (tid < N_SCAN_BLOCKS) ? blockSums[tid] : 0;
    __syncthreads();
    for (int off = 1; off < 128; off <<= 1) {
        int t = (tid < 128 && tid >= off) ? ssum[tid - off] : 0;
        __syncthreads();
        if (tid < 128) ssum[tid] += t;   // inclusive
        __syncthreads();
    }
    const int i = blockIdx.x * 256 + tid;
    if (i < N_NODES) {
        const int j = i >> 10;
        const int add = (j == 0) ? 0 : ssum[j - 1];
        const int s = starts[i] + add;
        starts[i] = s;
        cursor[i] = s;
    } else if (i == N_NODES) {
        starts[N_NODES] = N_EDGES;
    }
}

// ---------------------------------------------------------------------------
// Kernel 4: RANGE-partitioned bucket fill. R13 post-mortem: the r&7 partition
// cut WRITE only 53->42MB because buckets average 64B (one line) and starts[]
// is 8B-granular: nearly every line SPANS two adjacent rows' buckets, and
// r&7 puts adjacent rows on DIFFERENT XCDs -> boundary lines still bounced.
// Fix: XCD x owns the CONTIGUOUS row range [x*12500,(x+1)*12500) -> a
// boundary-spanning line is written by one XCD (except at 7 range edges).
// Each XCD's recs slab (~0.8MB contiguous) composes in its 4MiB L2.
// Edge streams stay NONTEMPORAL (8x re-read, ~37MB HBM, ~7us BW) so they
// don't evict the open partial recs lines.
// PREDICT: WRITE 41.8 -> ~9-11MB, dur 45 -> 15-22us.
// ---------------------------------------------------------------------------
__global__ __launch_bounds__(256) void fill_xcd_kernel(
    const int* __restrict__ erow, const int* __restrict__ ecol,
    const float* __restrict__ ew, int* __restrict__ cursor,
    uint2* __restrict__ recs) {
    const int xcd = blockIdx.x & 7;          // XCD this block lands on (m09)
    const int lo = xcd * ROWS_PER_XCD;       // contiguous row range owned
    const int hi = lo + ROWS_PER_XCD;
    const int chunk = blockIdx.x >> 3;       // edge chunk, same range as before
    const int base = (chunk * 256 + threadIdx.x) * 4;
    if (base + 3 < N_EDGES) {
        iv4 r = __builtin_nontemporal_load(
            reinterpret_cast<const iv4*>(erow + base));
        iv4 c = __builtin_nontemporal_load(
            reinterpret_cast<const iv4*>(ecol + base));
        fv4 wt = __builtin_nontemporal_load(
            reinterpret_cast<const fv4*>(ew + base));
        #pragma unroll
        for (int j = 0; j < 4; ++j) {
            const int rr = r[j];
            if (rr >= lo && rr < hi) {       // ~1/8 lanes active per j
                const int p = atomicAdd(&cursor[rr], 1);
                recs[p] = make_uint2((unsigned)c[j], __float_as_uint(wt[j]));
            }
        }
    } else {
        for (int e = base; e < N_EDGES; ++e) {
            const int rr = erow[e];
            if (rr >= lo && rr < hi) {
                const int p = atomicAdd(&cursor[rr], 1);
                recs[p] = make_uint2((unsigned)ecol[e], __float_as_uint(ew[e]));
            }
        }
    }
}

// ---------------------------------------------------------------------------
// Kernel 5: aggregate from fp16 xw. (UNCHANGED; below top-5 cutoff since R10.)
// ---------------------------------------------------------------------------
__global__ __launch_bounds__(256) void aggregate_h_kernel(
    const __half* __restrict__ xwh, const uint2* __restrict__ recs,
    const int* __restrict__ starts, const float* __restrict__ b,
    float* __restrict__ out) {
    const int lane = threadIdx.x & 63;
    const int g = lane >> 4;        // row slot within wave
    const int s = lane & 15;        // feature quad
    const int wave = (int)((blockIdx.x * blockDim.x + threadIdx.x) >> 6);
    const int nwaves = (int)((gridDim.x * (size_t)blockDim.x) >> 6);
    const float4 bias = reinterpret_cast<const float4*>(b)[s];
    const unsigned long long* recs8 =
        reinterpret_cast<const unsigned long long*>(recs);

    for (int r0 = wave * 4; r0 < N_NODES; r0 += nwaves * 4) {
        const int r = r0 + g;
        if (r < N_NODES) {
            const int st = starts[r];
            const int cnt = starts[r + 1] - st;
            float4 acc = bias;
            int k = 0;
            for (; k + 4 <= cnt; k += 4) {
                unsigned long long p0 = __builtin_nontemporal_load(recs8 + st + k + 0);
                unsigned long long p1 = __builtin_nontemporal_load(recs8 + st + k + 1);
                unsigned long long p2 = __builtin_nontemporal_load(recs8 + st + k + 2);
                unsigned long long p3 = __builtin_nontemporal_load(recs8 + st + k + 3);
                uint2 g0 = *reinterpret_cast<const uint2*>(
                    xwh + (size_t)(unsigned)p0 * FDIM + 4 * s);
                uint2 g1 = *reinterpret_cast<const uint2*>(
                    xwh + (size_t)(unsigned)p1 * FDIM + 4 * s);
                uint2 g2 = *reinterpret_cast<const uint2*>(
                    xwh + (size_t)(unsigned)p2 * FDIM + 4 * s);
                uint2 g3 = *reinterpret_cast<const uint2*>(
                    xwh + (size_t)(unsigned)p3 * FDIM + 4 * s);
                const float w0 = __uint_as_float((unsigned)(p0 >> 32));
                const float w1 = __uint_as_float((unsigned)(p1 >> 32));
                const float w2 = __uint_as_float((unsigned)(p2 >> 32));
                const float w3 = __uint_as_float((unsigned)(p3 >> 32));
                float2 a0 = __half22float2(*reinterpret_cast<__half2*>(&g0.x));
                float2 b0 = __half22float2(*reinterpret_cast<__half2*>(&g0.y));
                float2 a1 = __half22float2(*reinterpret_cast<__half2*>(&g1.x));
                float2 b1 = __half22float2(*reinterpret_cast<__half2*>(&g1.y));
                float2 a2 = __half22float2(*reinterpret_cast<__half2*>(&g2.x));
                float2 b2 = __half22float2(*reinterpret_cast<__half2*>(&g2.y));
                float2 a3 = __half22float2(*reinterpret_cast<__half2*>(&g3.x));
                float2 b3 = __half22float2(*reinterpret_cast<__half2*>(&g3.y));
                acc.x += a0.x * w0 + a1.x * w1 + a2.x * w2 + a3.x * w3;
                acc.y += a0.y * w0 + a1.y * w1 + a2.y * w2 + a3.y * w3;
                acc.z += b0.x * w0 + b1.x * w1 + b2.x * w2 + b3.x * w3;
                acc.w += b0.y * w0 + b1.y * w1 + b2.y * w2 + b3.y * w3;
            }
            for (; k < cnt; ++k) {
                unsigned long long p0 = __builtin_nontemporal_load(recs8 + st + k);
                uint2 g0 = *reinterpret_cast<const uint2*>(
                    xwh + (size_t)(unsigned)p0 * FDIM + 4 * s);
                const float w0 = __uint_as_float((unsigned)(p0 >> 32));
                float2 a0 = __half22float2(*reinterpret_cast<__half2*>(&g0.x));
                float2 b0 = __half22float2(*reinterpret_cast<__half2*>(&g0.y));
                acc.x += a0.x * w0; acc.y += a0.y * w0;
                acc.z += b0.x * w0; acc.w += b0.y * w0;
            }
            reinterpret_cast<float4*>(out + (size_t)r * FDIM)[s] = acc;
        }
    }
}

// --------------------------- atomic fallback (unused in practice) ----------
__global__ __launch_bounds__(256) void gemm_rm_kernel(
    const float* __restrict__ x, const float* __restrict__ w,
    float* __restrict__ xw) {
    const int lane = threadIdx.x & 63;
    float wr[FDIM];
    #pragma unroll
    for (int k = 0; k < FDIM; ++k) wr[k] = w[k * FDIM + lane];
    const int gwave = blockIdx.x * 4 + (threadIdx.x >> 6);
    const int nwaves = gridDim.x * 4;
    for (int row = gwave; row < N_NODES; row += nwaves) {
        const float4* xr = reinterpret_cast<const float4*>(x + (size_t)row * FDIM);
        float a0 = 0.f, a1 = 0.f, a2 = 0.f, a3 = 0.f;
        #pragma unroll
        for (int k0 = 0; k0 < FDIM / 4; ++k0) {
            float4 xv = xr[k0];
            a0 += xv.x * wr[4 * k0 + 0];
            a1 += xv.y * wr[4 * k0 + 1];
            a2 += xv.z * wr[4 * k0 + 2];
            a3 += xv.w * wr[4 * k0 + 3];
        }
        xw[(size_t)row * FDIM + lane] = (a0 + a1) + (a2 + a3);
    }
}

__global__ __launch_bounds__(256) void init_out_kernel(
    float* __restrict__ out, const float* __restrict__ b) {
    const float4* b4 = reinterpret_cast<const float4*>(b);
    float4* out4 = reinterpret_cast<float4*>(out);
    const size_t total = (size_t)N_NODES * FDIM / 4;
    size_t i = (size_t)blockIdx.x * blockDim.x + threadIdx.x;
    const size_t stride = (size_t)gridDim.x * blockDim.x;
    for (; i < total; i += stride) out4[i] = b4[i & 15];
}

__global__ __launch_bounds__(256) void scatter_kernel(
    const float* __restrict__ xw, const float* __restrict__ ew,
    const int* __restrict__ erow, const int* __restrict__ ecol,
    float* __restrict__ out) {
    const int lane = threadIdx.x & 63;
    const int g = lane >> 4;
    const int s = lane & 15;
    const int wave = (int)((blockIdx.x * blockDim.x + threadIdx.x) >> 6);
    const int nwaves = (int)((gridDim.x * (size_t)blockDim.x) >> 6);
    for (int e0 = wave * 4; e0 < N_EDGES; e0 += nwaves * 4) {
        const int e = e0 + g;
        if (e < N_EDGES) {
            const int c = ecol[e];
            const int r = erow[e];
            const float wgt = ew[e];
            const float4 v =
                reinterpret_cast<const float4*>(xw + (size_t)c * FDIM)[s];
            float* dst = out + (size_t)r * FDIM + 4 * s;
            atomicAdd(dst + 0, v.x * wgt);
            atomicAdd(dst + 1, v.y * wgt);
            atomicAdd(dst + 2, v.z * wgt);
            atomicAdd(dst + 3, v.w * wgt);
        }
    }
}

extern "C" void kernel_launch(void* const* d_in, const int* in_sizes, int n_in,
                              void* d_out, int out_size, void* d_ws, size_t ws_size,
                              hipStream_t stream) {
    const float* x  = (const float*)d_in[0];
    const float* w  = (const float*)d_in[1];
    const float* b  = (const float*)d_in[2];
    const float* ew = (const float*)d_in[3];
    const int* erow = (const int*)d_in[4];
    const int* ecol = (const int*)d_in[5];
    float* out = (float*)d_out;

    char* ws = (char*)d_ws;
    const size_t XWH_BYTES  = (size_t)N_NODES * FDIM * 2;      // 12.8 MB fp16
    const size_t REC_BYTES  = (size_t)N_EDGES * 8;             // 6.4 MB
    const size_t CNT_BYTES  = (size_t)N_NODES * 4;             // 0.4 MB
    const size_t ST_BYTES   = ((size_t)(N_NODES + 1) * 4 + 15) & ~(size_t)15;
    const size_t SUMS_BYTES = 512;
    const size_t NEED = XWH_BYTES + REC_BYTES + CNT_BYTES + ST_BYTES +
                        CNT_BYTES + SUMS_BYTES;                // ~20.9 MB

    if (ws_size >= NEED) {
        __half* xwh    = (__half*)ws;
        uint2* recs    = (uint2*)(ws + XWH_BYTES);
        int* count     = (int*)(ws + XWH_BYTES + REC_BYTES);
        int* starts    = (int*)(ws + XWH_BYTES + REC_BYTES + CNT_BYTES);
        int* cursor    = (int*)(ws + XWH_BYTES + REC_BYTES + CNT_BYTES + ST_BYTES);
        int* blockSums = (int*)(ws + XWH_BYTES + REC_BYTES + CNT_BYTES + ST_BYTES + CNT_BYTES);

        const int gE4 = (N_EDGES / 4 + 255) / 256;   // 782
        const int gN  = (N_NODES + 255) / 256 + 1;   // 392 (covers sentinel)

        hipMemsetAsync(count, 0, CNT_BYTES, stream);            // zero degrees
        gemm_hist_kernel<<<N_TILES, 256, 0, stream>>>(x, w, erow, xwh, count);
        scan_block_kernel<<<N_SCAN_BLOCKS, SCAN_BLOCK, 0, stream>>>(count, starts, blockSums);
        scanadd_kernel<<<gN, 256, 0, stream>>>(starts, blockSums, cursor);
        fill_xcd_kernel<<<gE4 * 8, 256, 0, stream>>>(erow, ecol, ew, cursor, recs);
        aggregate_h_kernel<<<2048, 256, 0, stream>>>(xwh, recs, starts, b, out);
    } else {
        // fallback: f32 xw + atomic scatter (needs 25.6 MB)
        float* xw = (float*)ws;
        gemm_rm_kernel<<<2048, 256, 0, stream>>>(x, w, xw);
        init_out_kernel<<<2048, 256, 0, stream>>>(out, b);
        scatter_kernel<<<2048, 256, 0, stream>>>(xw, ew, erow, ecol, out);
    }
}